// Round 15
// baseline (561.271 us; speedup 1.0000x reference)
//
#include <hip/hip_runtime.h>
#include <stdint.h>

typedef __attribute__((ext_vector_type(4))) float f32x4;
typedef __attribute__((ext_vector_type(16))) float f32x16;
typedef __attribute__((ext_vector_type(8))) short bf16x8;

constexpr int S_ = 2048;
constexpr int D_ = 128;
constexpr int BH = 32;
constexpr int KB = 64;          // kv rows per tile
constexpr int NT = S_ / KB;     // 32 tiles
// fold 1/sqrt(128) * log2(e) into Q so scores are in log2 domain
constexpr float QSCALE = 0.08838834764831845f * 1.4426950408889634f;

__device__ __forceinline__ short f2bf(float f) {
  uint32_t u = __float_as_uint(f);
  u += 0x7fffu + ((u >> 16) & 1u);
  return (short)(u >> 16);
}

// ===== prep 1: K -> bf16 FRAGMENT-MAJOR: kf[bh][chunk32][s8][lane64][8] =====
// frag element: (lane=hi*32+l32, j) -> K[c*32 + l32][s*16 + hi*8 + j]
__global__ void prep_kf(const float* __restrict__ k, short* __restrict__ kf) {
  __shared__ short Lt[32][132];
  const int bh = blockIdx.x >> 6;
  const int c = blockIdx.x & 63;
  const int t = threadIdx.x;
#pragma unroll
  for (int i = 0; i < 4; ++i) {
    int g = t + 256 * i;                   // 1024 float4 granules
    int r = g >> 5, c4 = g & 31;
    float4 f = reinterpret_cast<const float4*>(k)[((size_t)bh * S_ + c * 32 + r) * 32 + c4];
    short* d = &Lt[r][c4 * 4];
    d[0] = f2bf(f.x); d[1] = f2bf(f.y); d[2] = f2bf(f.z); d[3] = f2bf(f.w);
  }
  __syncthreads();
#pragma unroll
  for (int i = 0; i < 2; ++i) {
    int gw = t + 256 * i;                  // 512 granules
    int s = gw >> 6, lane = gw & 63;
    int l32 = lane & 31, hi = lane >> 5;
    bf16x8 o;
#pragma unroll
    for (int j = 0; j < 8; ++j) o[j] = Lt[l32][s * 16 + hi * 8 + j];
    *reinterpret_cast<bf16x8*>(
        &kf[((size_t)(bh * 64 + c) * 8 + s) * 512 + lane * 8]) = o;
  }
}

// ===== prep 2: V -> bf16 FRAGMENT-MAJOR: vf[bh][tile64][f16][lane64][8] =====
// frag f = ks2*4 + d0; element: (lane, j) -> V[t*64 + (ks2*2+hi)*8 + j][d0*32 + l32]
__global__ void prep_vf(const float* __restrict__ v, short* __restrict__ vf) {
  __shared__ short Lt[64][132];
  const int bh = blockIdx.x >> 5;
  const int tt = blockIdx.x & 31;
  const int t = threadIdx.x;
#pragma unroll
  for (int i = 0; i < 8; ++i) {
    int g = t + 256 * i;                   // 2048 float4 granules
    int r = g >> 5, c4 = g & 31;
    float4 f = reinterpret_cast<const float4*>(v)[((size_t)bh * S_ + tt * 64 + r) * 32 + c4];
    short* d = &Lt[r][c4 * 4];
    d[0] = f2bf(f.x); d[1] = f2bf(f.y); d[2] = f2bf(f.z); d[3] = f2bf(f.w);
  }
  __syncthreads();
#pragma unroll
  for (int i = 0; i < 4; ++i) {
    int gw = t + 256 * i;                  // 1024 granules
    int f = gw >> 6, lane = gw & 63;
    int ks2 = f >> 2, d0 = f & 3;
    int l32 = lane & 31, hi = lane >> 5;
    bf16x8 o;
#pragma unroll
    for (int j = 0; j < 8; ++j) o[j] = Lt[(ks2 * 2 + hi) * 8 + j][d0 * 32 + l32];
    *reinterpret_cast<bf16x8*>(
        &vf[((size_t)(bh * 32 + tt) * 16 + f) * 512 + lane * 8]) = o;
  }
}

// ===== v15: v12 (barrier-free, frag-major operands) at 4 blocks/CU =====
// 4 waves x 32q per 256-thr block, grid 512, __launch_bounds__(256,4): 16 waves/CU
// free-running (no barriers) -> waves naturally de-phase and interleave MFMA/VALU/L1.
// lsum in VALU (frees loacc regs under the 128-VGPR cap). No-max softmax.
__global__ __launch_bounds__(256, 4) void attn_fwd_v15(
    const float* __restrict__ q, const short* __restrict__ kf,
    const short* __restrict__ vf, float* __restrict__ out)
{
  const int lid = blockIdx.x;
  const int swz = (lid & 7) * 64 + (lid >> 3);   // bijective: 512 % 8 == 0
  const int qt = swz & 15;
  const int bh = swz >> 4;

  const int tid = threadIdx.x;
  const int wid = tid >> 6;
  const int lane = tid & 63;
  const int l32 = lane & 31;
  const int hi = lane >> 5;

  const int qrow = qt * 128 + wid * 32 + l32;

  // ---- Q B-frag: bq[s][j] = Q[qrow][s*16 + hi*8 + j], scaled (read once) ----
  bf16x8 bq[8];
  {
    const float* qg_ = q + ((size_t)bh * S_ + qrow) * D_ + hi * 8;
#pragma unroll
    for (int s = 0; s < 8; ++s) {
      float4 f0 = *reinterpret_cast<const float4*>(qg_ + s * 16);
      float4 f1 = *reinterpret_cast<const float4*>(qg_ + s * 16 + 4);
      bf16x8 a;
      a[0] = f2bf(f0.x * QSCALE); a[1] = f2bf(f0.y * QSCALE);
      a[2] = f2bf(f0.z * QSCALE); a[3] = f2bf(f0.w * QSCALE);
      a[4] = f2bf(f1.x * QSCALE); a[5] = f2bf(f1.y * QSCALE);
      a[6] = f2bf(f1.z * QSCALE); a[7] = f2bf(f1.w * QSCALE);
      bq[s] = a;
    }
  }

  const short* kbase = kf + (size_t)bh * 64 * 8 * 512 + lane * 8;
  const short* vbase = vf + (size_t)bh * 32 * 16 * 512 + lane * 8;

  f32x16 oacc[4];
#pragma unroll
  for (int d0 = 0; d0 < 4; ++d0)
#pragma unroll
    for (int r = 0; r < 16; ++r) oacc[d0][r] = 0.f;
  float lsum = 0.f;

  for (int t = 0; t < NT; ++t) {
    const short* kt = kbase + (size_t)t * 16 * 512;
    const short* vt_ = vbase + (size_t)t * 16 * 512;

    // ---- K frags: 16 contiguous-1KB coalesced loads ----
    bf16x8 kreg[16];
#pragma unroll
    for (int g = 0; g < 16; ++g)
      kreg[g] = *reinterpret_cast<const bf16x8*>(kt + g * 512);

    // ---- QK^T(t): S^T[kv64][q32] ----
    f32x16 sf0, sf1;
#pragma unroll
    for (int r = 0; r < 16; ++r) { sf0[r] = 0.f; sf1[r] = 0.f; }
    __builtin_amdgcn_s_setprio(1);
#pragma unroll
    for (int s = 0; s < 8; ++s) {
      sf0 = __builtin_amdgcn_mfma_f32_32x32x16_bf16(kreg[s], bq[s], sf0, 0, 0, 0);
      sf1 = __builtin_amdgcn_mfma_f32_32x32x16_bf16(kreg[8 + s], bq[s], sf1, 0, 0, 0);
    }
    __builtin_amdgcn_s_setprio(0);

    // ---- V frags issued now; latency hidden under softmax ----
    bf16x8 vreg[16];
#pragma unroll
    for (int f = 0; f < 16; ++f)
      vreg[f] = *reinterpret_cast<const bf16x8*>(vt_ + f * 512);

    // ---- softmax(t): no-max, exp2 direct; pack to PV B-frags in registers ----
    bf16x8 pfrag[4];
#define MAKE_P(SF, F0)                                                          \
    {                                                                           \
      uint32_t w[8];                                                            \
      _Pragma("unroll")                                                         \
      for (int i2 = 0; i2 < 8; ++i2) {                                          \
        float e0 = exp2f(SF[2 * i2]);                                           \
        float e1 = exp2f(SF[2 * i2 + 1]);                                       \
        lsum += e0 + e1;                                                        \
        asm("v_cvt_pk_bf16_f32 %0, %1, %2" : "=v"(w[i2]) : "v"(e0), "v"(e1));   \
      }                                                                         \
      asm("v_permlane32_swap_b32 %0, %1" : "+v"(w[0]), "+v"(w[2]));             \
      asm("v_permlane32_swap_b32 %0, %1" : "+v"(w[1]), "+v"(w[3]));             \
      asm("v_permlane32_swap_b32 %0, %1" : "+v"(w[4]), "+v"(w[6]));             \
      asm("v_permlane32_swap_b32 %0, %1" : "+v"(w[5]), "+v"(w[7]));             \
      union { int4 i4; bf16x8 b; } u0, u1;                                      \
      u0.i4 = (int4){(int)w[0], (int)w[1], (int)w[2], (int)w[3]};               \
      u1.i4 = (int4){(int)w[4], (int)w[5], (int)w[6], (int)w[7]};               \
      pfrag[F0] = u0.b; pfrag[F0 + 1] = u1.b;                                   \
    }
    MAKE_P(sf0, 0)
    MAKE_P(sf1, 2)
#undef MAKE_P

    // ---- PV(t): O^T += V*P^T ----
    __builtin_amdgcn_s_setprio(1);
#pragma unroll
    for (int ks2 = 0; ks2 < 4; ++ks2)
#pragma unroll
      for (int d0 = 0; d0 < 4; ++d0)
        oacc[d0] = __builtin_amdgcn_mfma_f32_32x32x16_bf16(
            vreg[ks2 * 4 + d0], pfrag[ks2], oacc[d0], 0, 0, 0);
    __builtin_amdgcn_s_setprio(0);
  }

  // ---- epilogue ----
  lsum += __shfl_xor(lsum, 32, 64);
  const float inv = 1.0f / lsum;
  float* ob = out + ((size_t)bh * S_ + qrow) * D_;
#pragma unroll
  for (int d0 = 0; d0 < 4; ++d0)
#pragma unroll
    for (int r2 = 0; r2 < 4; ++r2) {
      float4 o4 = {oacc[d0][r2 * 4 + 0] * inv, oacc[d0][r2 * 4 + 1] * inv,
                   oacc[d0][r2 * 4 + 2] * inv, oacc[d0][r2 * 4 + 3] * inv};
      *reinterpret_cast<float4*>(ob + d0 * 32 + r2 * 8 + hi * 4) = o4;
    }
}

// ================= fallback (R1 kernel) if ws too small =================
__global__ __launch_bounds__(256, 4) void attn_fwd_v1(
    const float* __restrict__ q, const float* __restrict__ k,
    const float* __restrict__ v, float* __restrict__ out)
{
  __shared__ __align__(16) short Klds[32 * 128];
  __shared__ __align__(16) short Vlds[128 * 40];
  __shared__ __align__(16) short Plds[4][16 * 40];
  const int lid = blockIdx.x;
  const int swz = (lid & 7) * 128 + (lid >> 3);
  const int qt = swz & 31;
  const int bh = swz >> 5;
  const int tid = threadIdx.x;
  const int wid = tid >> 6;
  const int lane = tid & 63;
  const int l16 = lane & 15;
  const int lhi = lane >> 4;
  const int qrow0 = qt * 64 + wid * 16;
  const float* qg = q + ((size_t)bh * S_ + qrow0 + l16) * D_;
  const float* kg = k + (size_t)bh * S_ * D_;
  const float* vg = v + (size_t)bh * S_ * D_;
  bf16x8 aq[4];
#pragma unroll
  for (int ks = 0; ks < 4; ++ks) {
    const float* p = qg + ks * 32 + lhi * 8;
    float4 f0 = *reinterpret_cast<const float4*>(p);
    float4 f1 = *reinterpret_cast<const float4*>(p + 4);
    bf16x8 a;
    a[0] = f2bf(f0.x * QSCALE); a[1] = f2bf(f0.y * QSCALE);
    a[2] = f2bf(f0.z * QSCALE); a[3] = f2bf(f0.w * QSCALE);
    a[4] = f2bf(f1.x * QSCALE); a[5] = f2bf(f1.y * QSCALE);
    a[6] = f2bf(f1.z * QSCALE); a[7] = f2bf(f1.w * QSCALE);
    aq[ks] = a;
  }
  float mrow[4], lrow[4];
  f32x4 oacc[8];
#pragma unroll
  for (int r = 0; r < 4; ++r) { mrow[r] = -1e30f; lrow[r] = 0.f; }
#pragma unroll
  for (int i = 0; i < 8; ++i) oacc[i] = (f32x4){0.f, 0.f, 0.f, 0.f};
  for (int t = 0; t < S_ / 32; ++t) {
    const int kv0 = t * 32;
    __syncthreads();
#pragma unroll
    for (int i = 0; i < 2; ++i) {
      const int g = tid * 2 + i;
      const int row = g >> 4;
      const int c8 = g & 15;
      const float* ksrc = kg + (size_t)(kv0 + row) * D_ + c8 * 8;
      float4 f0 = *reinterpret_cast<const float4*>(ksrc);
      float4 f1 = *reinterpret_cast<const float4*>(ksrc + 4);
      bf16x8 kk;
      kk[0] = f2bf(f0.x); kk[1] = f2bf(f0.y); kk[2] = f2bf(f0.z); kk[3] = f2bf(f0.w);
      kk[4] = f2bf(f1.x); kk[5] = f2bf(f1.y); kk[6] = f2bf(f1.z); kk[7] = f2bf(f1.w);
      *reinterpret_cast<bf16x8*>(
          &Klds[row * D_ + ((c8 * 8) ^ ((row & 7) << 3))]) = kk;
      const float* vsrc = vg + (size_t)(kv0 + row) * D_ + c8 * 8;
      float4 g0 = *reinterpret_cast<const float4*>(vsrc);
      float4 g1 = *reinterpret_cast<const float4*>(vsrc + 4);
      const int dbase = c8 * 8;
      Vlds[(dbase + 0) * 40 + row] = f2bf(g0.x);
      Vlds[(dbase + 1) * 40 + row] = f2bf(g0.y);
      Vlds[(dbase + 2) * 40 + row] = f2bf(g0.z);
      Vlds[(dbase + 3) * 40 + row] = f2bf(g0.w);
      Vlds[(dbase + 4) * 40 + row] = f2bf(g1.x);
      Vlds[(dbase + 5) * 40 + row] = f2bf(g1.y);
      Vlds[(dbase + 6) * 40 + row] = f2bf(g1.z);
      Vlds[(dbase + 7) * 40 + row] = f2bf(g1.w);
    }
    __syncthreads();
    f32x4 sfrag[2];
#pragma unroll
    for (int kb = 0; kb < 2; ++kb) {
      f32x4 acc = (f32x4){0.f, 0.f, 0.f, 0.f};
#pragma unroll
      for (int ks = 0; ks < 4; ++ks) {
        const int rowk = kb * 16 + l16;
        bf16x8 bk = *reinterpret_cast<const bf16x8*>(
            &Klds[rowk * D_ + (((ks * 4 + lhi) * 8) ^ ((rowk & 7) << 3))]);
        acc = __builtin_amdgcn_mfma_f32_16x16x32_bf16(aq[ks], bk, acc, 0, 0, 0);
      }
      sfrag[kb] = acc;
    }
    float mt[4];
#pragma unroll
    for (int r = 0; r < 4; ++r) mt[r] = fmaxf(sfrag[0][r], sfrag[1][r]);
#pragma unroll
    for (int off = 1; off < 16; off <<= 1)
#pragma unroll
      for (int r = 0; r < 4; ++r) mt[r] = fmaxf(mt[r], __shfl_xor(mt[r], off, 64));
    float al[4], ps[4];
#pragma unroll
    for (int r = 0; r < 4; ++r) {
      float mn = fmaxf(mrow[r], mt[r]);
      al[r] = exp2f(mrow[r] - mn);
      mrow[r] = mn;
      ps[r] = 0.f;
    }
#pragma unroll
    for (int kb = 0; kb < 2; ++kb)
#pragma unroll
      for (int r = 0; r < 4; ++r) {
        float p = exp2f(sfrag[kb][r] - mrow[r]);
        ps[r] += p;
        Plds[wid][(lhi * 4 + r) * 40 + kb * 16 + l16] = f2bf(p);
      }
#pragma unroll
    for (int off = 1; off < 16; off <<= 1)
#pragma unroll
      for (int r = 0; r < 4; ++r) ps[r] += __shfl_xor(ps[r], off, 64);
#pragma unroll
    for (int r = 0; r < 4; ++r) lrow[r] = lrow[r] * al[r] + ps[r];
#pragma unroll
    for (int i = 0; i < 8; ++i)
#pragma unroll
      for (int r = 0; r < 4; ++r) oacc[i][r] *= al[r];
    bf16x8 ap = *reinterpret_cast<const bf16x8*>(&Plds[wid][l16 * 40 + lhi * 8]);
#pragma unroll
    for (int d0 = 0; d0 < 8; ++d0) {
      bf16x8 bv = *reinterpret_cast<const bf16x8*>(
          &Vlds[(d0 * 16 + l16) * 40 + lhi * 8]);
      oacc[d0] = __builtin_amdgcn_mfma_f32_16x16x32_bf16(ap, bv, oacc[d0], 0, 0, 0);
    }
  }
#pragma unroll
  for (int r = 0; r < 4; ++r) {
    float inv = 1.0f / lrow[r];
    float* orow = out + ((size_t)bh * S_ + qrow0 + lhi * 4 + r) * D_ + l16;
#pragma unroll
    for (int d0 = 0; d0 < 8; ++d0) orow[d0 * 16] = oacc[d0][r] * inv;
  }
}

extern "C" void kernel_launch(void* const* d_in, const int* in_sizes, int n_in,
                              void* d_out, int out_size, void* d_ws, size_t ws_size,
                              hipStream_t stream) {
  (void)in_sizes; (void)n_in; (void)out_size;
  const float* q = (const float*)d_in[0];
  const float* k = (const float*)d_in[1];
  const float* v = (const float*)d_in[2];
  float* o = (float*)d_out;
  const size_t NEL = (size_t)BH * S_ * D_;
  const size_t need = NEL * 2 * sizeof(short);   // kf + vf, 33.6 MB
  if (ws_size >= need) {
    short* kfb = (short*)d_ws;
    short* vfb = kfb + NEL;
    hipLaunchKernelGGL(prep_kf, dim3(2048), dim3(256), 0, stream, k, kfb);
    hipLaunchKernelGGL(prep_vf, dim3(1024), dim3(256), 0, stream, v, vfb);
    hipLaunchKernelGGL(attn_fwd_v15, dim3(512), dim3(256), 0, stream, q, kfb, vfb, o);
  } else {
    hipLaunchKernelGGL(attn_fwd_v1, dim3(1024), dim3(256), 0, stream, q, k, v, o);
  }
}

// Round 16
// 108.352 us; speedup vs baseline: 5.1801x; 5.1801x over previous
//
#include <hip/hip_runtime.h>
#include <stdint.h>

typedef __attribute__((ext_vector_type(4))) float f32x4;
typedef __attribute__((ext_vector_type(16))) float f32x16;
typedef __attribute__((ext_vector_type(8))) short bf16x8;

constexpr int S_ = 2048;
constexpr int D_ = 128;
constexpr int BH = 32;
constexpr int KB = 64;          // kv rows per tile
constexpr int NT = S_ / KB;     // 32 tiles
// fold 1/sqrt(128) * log2(e) into Q so scores are in log2 domain
constexpr float QSCALE = 0.08838834764831845f * 1.4426950408889634f;

__device__ __forceinline__ short f2bf(float f) {
  uint32_t u = __float_as_uint(f);
  u += 0x7fffu + ((u >> 16) & 1u);
  return (short)(u >> 16);
}

__device__ __forceinline__ void gll16(const void* g, void* l) {
  __builtin_amdgcn_global_load_lds(
      (const __attribute__((address_space(1))) void*)g,
      (__attribute__((address_space(3))) void*)l, 16, 0, 0);
}

// ================= prep 1: k -> bf16 row-major (for gll staging) =================
__global__ void prep_k(const float* __restrict__ k, short* __restrict__ kb) {
  const size_t N8 = (size_t)BH * S_ * D_ / 8;
  size_t i = (size_t)blockIdx.x * blockDim.x + threadIdx.x;
  const size_t stride = (size_t)gridDim.x * blockDim.x;
  for (; i < N8; i += stride) {
    float4 a = reinterpret_cast<const float4*>(k)[i * 2];
    float4 b = reinterpret_cast<const float4*>(k)[i * 2 + 1];
    bf16x8 o;
    o[0] = f2bf(a.x); o[1] = f2bf(a.y); o[2] = f2bf(a.z); o[3] = f2bf(a.w);
    o[4] = f2bf(b.x); o[5] = f2bf(b.y); o[6] = f2bf(b.z); o[7] = f2bf(b.w);
    reinterpret_cast<bf16x8*>(kb)[i] = o;
  }
}

// ================= prep 2: v -> bf16 transposed per head: vt[bh][d][s] =================
__global__ void prep_vt(const float* __restrict__ v, short* __restrict__ vt) {
  __shared__ __align__(16) short Lt[64][136];
  const int bh = blockIdx.x >> 5;
  const int s0 = (blockIdx.x & 31) * 64;
  const int t = threadIdx.x;
#pragma unroll
  for (int i = 0; i < 4; ++i) {
    int g = t + 256 * i;
    int r = g >> 4, c8 = g & 15;
    const float* src = v + ((size_t)bh * S_ + s0 + r) * D_ + c8 * 8;
    float4 f0 = *reinterpret_cast<const float4*>(src);
    float4 f1 = *reinterpret_cast<const float4*>(src + 4);
    bf16x8 o;
    o[0] = f2bf(f0.x); o[1] = f2bf(f0.y); o[2] = f2bf(f0.z); o[3] = f2bf(f0.w);
    o[4] = f2bf(f1.x); o[5] = f2bf(f1.y); o[6] = f2bf(f1.z); o[7] = f2bf(f1.w);
    *reinterpret_cast<bf16x8*>(&Lt[r][c8 * 8]) = o;
  }
  __syncthreads();
#pragma unroll
  for (int i = 0; i < 4; ++i) {
    int g = t * 4 + i;
    int d = g >> 3, s8 = g & 7;
    bf16x8 o;
#pragma unroll
    for (int j = 0; j < 8; ++j) o[j] = Lt[s8 * 8 + j][d];
    *reinterpret_cast<bf16x8*>(&vt[((size_t)bh * D_ + d) * S_ + s0 + s8 * 8]) = o;
  }
}

// ===== v16: v9 + T3-lite sub-phase interleave (QKa|PVa|SMa|QKb|PVb|SMb) =====
// 8 waves x 32q, KVBLK=64, K triple- / V quad-buffered gll, stage-before-barrier
// + counted vmcnt(4). Two P-frag sets (pprev/pnew) decouple PV(t-1) from SM(t).
__global__ __launch_bounds__(512, 1) void attn_fwd_v16(
    const float* __restrict__ q, const short* __restrict__ kbf,
    const short* __restrict__ vt, float* __restrict__ out)
{
  __shared__ __align__(16) short Klds[3][8192];   // 3 x 16 KB
  __shared__ __align__(16) short Vlds[4][8192];   // 4 x 16 KB

  const int lid = blockIdx.x;
  const int swz = (lid & 7) * 32 + (lid >> 3);   // bijective: 256 % 8 == 0
  const int qt = swz & 7;
  const int bh = swz >> 3;

  const int tid = threadIdx.x;
  const int wid = tid >> 6;
  const int lane = tid & 63;
  const int l32 = lane & 31;
  const int hi = lane >> 5;

  const int qrow = qt * 256 + wid * 32 + l32;

  // ---- Q B-frag: bq[s][j] = Q[qrow][s*16 + hi*8 + j], scaled (read once) ----
  bf16x8 bq[8];
  {
    const float* qg_ = q + ((size_t)bh * S_ + qrow) * D_ + hi * 8;
#pragma unroll
    for (int s = 0; s < 8; ++s) {
      float4 f0 = *reinterpret_cast<const float4*>(qg_ + s * 16);
      float4 f1 = *reinterpret_cast<const float4*>(qg_ + s * 16 + 4);
      bf16x8 a;
      a[0] = f2bf(f0.x * QSCALE); a[1] = f2bf(f0.y * QSCALE);
      a[2] = f2bf(f0.z * QSCALE); a[3] = f2bf(f0.w * QSCALE);
      a[4] = f2bf(f1.x * QSCALE); a[5] = f2bf(f1.y * QSCALE);
      a[6] = f2bf(f1.z * QSCALE); a[7] = f2bf(f1.w * QSCALE);
      bq[s] = a;
    }
  }

  const short* kg = kbf + (size_t)bh * S_ * D_;
  const short* vg = vt + (size_t)bh * D_ * S_;

  // staging: wave wid handles gll granule-groups g = 2*wid, 2*wid+1 for K and V
  int kofs[2], vofs[2];
#pragma unroll
  for (int j = 0; j < 2; ++j) {
    const int g = wid * 2 + j;
    kofs[j] = lane * D_ + g * 8;                  // K[kv=lane][d8=g]
    const int G = g * 64 + lane;
    vofs[j] = (G & 127) * S_ + (G >> 7) * 8;      // Vt[d=G&127][kv8=G>>7]
  }
  auto stage = [&](int t) {
    const short* ks = kg + (size_t)(t * KB) * D_;
    const short* vs = vg + t * KB;
    short* kd = &Klds[t % 3][wid * 1024];
    short* vd = &Vlds[t & 3][wid * 1024];
    gll16(ks + kofs[0], kd);
    gll16(ks + kofs[1], kd + 512);
    gll16(vs + vofs[0], vd);
    gll16(vs + vofs[1], vd + 512);
  };

  f32x16 oacc[4], loacc;
#pragma unroll
  for (int d0 = 0; d0 < 4; ++d0)
#pragma unroll
    for (int r = 0; r < 16; ++r) oacc[d0][r] = 0.f;
#pragma unroll
  for (int r = 0; r < 16; ++r) loacc[r] = 0.f;

  union { uint32_t u[4]; bf16x8 b; } onesu;
#pragma unroll
  for (int i = 0; i < 4; ++i) onesu.u[i] = 0x3F803F80u;   // bf16 1.0 pairs

  bf16x8 pprev[4], pnew[4];   // P-frags: previous tile (PV input) / being built

#define MAKE_P(SF, DST, F0)                                                     \
    {                                                                           \
      uint32_t w[8];                                                            \
      _Pragma("unroll")                                                         \
      for (int i2 = 0; i2 < 8; ++i2) {                                          \
        float e0 = exp2f(SF[2 * i2]);                                           \
        float e1 = exp2f(SF[2 * i2 + 1]);                                       \
        asm("v_cvt_pk_bf16_f32 %0, %1, %2" : "=v"(w[i2]) : "v"(e0), "v"(e1));   \
      }                                                                         \
      asm("v_permlane32_swap_b32 %0, %1" : "+v"(w[0]), "+v"(w[2]));             \
      asm("v_permlane32_swap_b32 %0, %1" : "+v"(w[1]), "+v"(w[3]));             \
      asm("v_permlane32_swap_b32 %0, %1" : "+v"(w[4]), "+v"(w[6]));             \
      asm("v_permlane32_swap_b32 %0, %1" : "+v"(w[5]), "+v"(w[7]));             \
      union { int4 i4; bf16x8 b; } u0, u1;                                      \
      u0.i4 = (int4){(int)w[0], (int)w[1], (int)w[2], (int)w[3]};               \
      u1.i4 = (int4){(int)w[4], (int)w[5], (int)w[6], (int)w[7]};               \
      DST[F0] = u0.b; DST[F0 + 1] = u1.b;                                       \
    }

#define PV_HALF(PSRC, KS0)                                                      \
    {                                                                           \
      __builtin_amdgcn_s_setprio(1);                                            \
      _Pragma("unroll")                                                         \
      for (int ks2 = (KS0); ks2 < (KS0) + 2; ++ks2) {                           \
        _Pragma("unroll")                                                       \
        for (int d0 = 0; d0 < 4; ++d0) {                                        \
          bf16x8 av = *reinterpret_cast<const bf16x8*>(                         \
              &Vp[((ks2 * 2 + hi) * 128 + d0 * 32 + l32) * 8]);                 \
          oacc[d0] = __builtin_amdgcn_mfma_f32_32x32x16_bf16(av, PSRC[ks2], oacc[d0], 0, 0, 0); \
        }                                                                       \
        loacc = __builtin_amdgcn_mfma_f32_32x32x16_bf16(onesu.b, PSRC[ks2], loacc, 0, 0, 0);    \
      }                                                                         \
      __builtin_amdgcn_s_setprio(0);                                            \
    }

  stage(0);
  for (int t = 0; t < NT; ++t) {
    // ---- counted-vmcnt barrier (v9): stage(t+1) first, wait only tile t's 4 gll ----
    if (t + 1 < NT) {
      stage(t + 1);
      __builtin_amdgcn_sched_barrier(0);
      asm volatile("s_waitcnt vmcnt(4)" ::: "memory");
    } else {
      __builtin_amdgcn_sched_barrier(0);
      asm volatile("s_waitcnt vmcnt(0)" ::: "memory");
    }
    __builtin_amdgcn_sched_barrier(0);
    __builtin_amdgcn_s_barrier();
    __builtin_amdgcn_sched_barrier(0);

    const short* Kb = &Klds[t % 3][0];
    const short* Vp = &Vlds[(t + 3) & 3][0];     // V of tile t-1

    // ======== sub-phase a: QK on kv[0:32] | PV(t-1) ks2=0,1 | SM_a ========
    f32x16 sf0;
#pragma unroll
    for (int r = 0; r < 16; ++r) sf0[r] = 0.f;
    __builtin_amdgcn_s_setprio(1);
#pragma unroll
    for (int s = 0; s < 8; ++s) {
      bf16x8 a0 = *reinterpret_cast<const bf16x8*>(&Kb[((s * 2 + hi) * 64 + l32) * 8]);
      sf0 = __builtin_amdgcn_mfma_f32_32x32x16_bf16(a0, bq[s], sf0, 0, 0, 0);
    }
    __builtin_amdgcn_s_setprio(0);
    if (t > 0) PV_HALF(pprev, 0)
    MAKE_P(sf0, pnew, 0)

    // ======== sub-phase b: QK on kv[32:64] | PV(t-1) ks2=2,3 | SM_b ========
    f32x16 sf1;
#pragma unroll
    for (int r = 0; r < 16; ++r) sf1[r] = 0.f;
    __builtin_amdgcn_s_setprio(1);
#pragma unroll
    for (int s = 0; s < 8; ++s) {
      bf16x8 a1 = *reinterpret_cast<const bf16x8*>(&Kb[((s * 2 + hi) * 64 + 32 + l32) * 8]);
      sf1 = __builtin_amdgcn_mfma_f32_32x32x16_bf16(a1, bq[s], sf1, 0, 0, 0);
    }
    __builtin_amdgcn_s_setprio(0);
    if (t > 0) PV_HALF(pprev, 2)
    MAKE_P(sf1, pnew, 2)

    // ---- roll P pipeline ----
#pragma unroll
    for (int i = 0; i < 4; ++i) pprev[i] = pnew[i];
  }

  // ---- drain: PV(NT-1); V staged at t=NT-1, drained by final vmcnt(0)+barrier ----
  {
    const short* Vp = &Vlds[(NT - 1) & 3][0];
    PV_HALF(pprev, 0)
    PV_HALF(pprev, 2)
  }
#undef PV_HALF
#undef MAKE_P

  // ---- epilogue: l = loacc[0] (all rows identical); O^T frag -> out[q][d] ----
  const float inv = 1.0f / loacc[0];
  float* ob = out + ((size_t)bh * S_ + qrow) * D_;
#pragma unroll
  for (int d0 = 0; d0 < 4; ++d0)
#pragma unroll
    for (int r2 = 0; r2 < 4; ++r2) {
      float4 o4 = {oacc[d0][r2 * 4 + 0] * inv, oacc[d0][r2 * 4 + 1] * inv,
                   oacc[d0][r2 * 4 + 2] * inv, oacc[d0][r2 * 4 + 3] * inv};
      *reinterpret_cast<float4*>(ob + d0 * 32 + r2 * 8 + hi * 4) = o4;
    }
}

// ================= fallback (R1 kernel) if ws too small =================
__global__ __launch_bounds__(256, 4) void attn_fwd_v1(
    const float* __restrict__ q, const float* __restrict__ k,
    const float* __restrict__ v, float* __restrict__ out)
{
  __shared__ __align__(16) short Klds[32 * 128];
  __shared__ __align__(16) short Vlds[128 * 40];
  __shared__ __align__(16) short Plds[4][16 * 40];
  const int lid = blockIdx.x;
  const int swz = (lid & 7) * 128 + (lid >> 3);
  const int qt = swz & 31;
  const int bh = swz >> 5;
  const int tid = threadIdx.x;
  const int wid = tid >> 6;
  const int lane = tid & 63;
  const int l16 = lane & 15;
  const int lhi = lane >> 4;
  const int qrow0 = qt * 64 + wid * 16;
  const float* qg = q + ((size_t)bh * S_ + qrow0 + l16) * D_;
  const float* kg = k + (size_t)bh * S_ * D_;
  const float* vg = v + (size_t)bh * S_ * D_;
  bf16x8 aq[4];
#pragma unroll
  for (int ks = 0; ks < 4; ++ks) {
    const float* p = qg + ks * 32 + lhi * 8;
    float4 f0 = *reinterpret_cast<const float4*>(p);
    float4 f1 = *reinterpret_cast<const float4*>(p + 4);
    bf16x8 a;
    a[0] = f2bf(f0.x * QSCALE); a[1] = f2bf(f0.y * QSCALE);
    a[2] = f2bf(f0.z * QSCALE); a[3] = f2bf(f0.w * QSCALE);
    a[4] = f2bf(f1.x * QSCALE); a[5] = f2bf(f1.y * QSCALE);
    a[6] = f2bf(f1.z * QSCALE); a[7] = f2bf(f1.w * QSCALE);
    aq[ks] = a;
  }
  float mrow[4], lrow[4];
  f32x4 oacc[8];
#pragma unroll
  for (int r = 0; r < 4; ++r) { mrow[r] = -1e30f; lrow[r] = 0.f; }
#pragma unroll
  for (int i = 0; i < 8; ++i) oacc[i] = (f32x4){0.f, 0.f, 0.f, 0.f};
  for (int t = 0; t < S_ / 32; ++t) {
    const int kv0 = t * 32;
    __syncthreads();
#pragma unroll
    for (int i = 0; i < 2; ++i) {
      const int g = tid * 2 + i;
      const int row = g >> 4;
      const int c8 = g & 15;
      const float* ksrc = kg + (size_t)(kv0 + row) * D_ + c8 * 8;
      float4 f0 = *reinterpret_cast<const float4*>(ksrc);
      float4 f1 = *reinterpret_cast<const float4*>(ksrc + 4);
      bf16x8 kk;
      kk[0] = f2bf(f0.x); kk[1] = f2bf(f0.y); kk[2] = f2bf(f0.z); kk[3] = f2bf(f0.w);
      kk[4] = f2bf(f1.x); kk[5] = f2bf(f1.y); kk[6] = f2bf(f1.z); kk[7] = f2bf(f1.w);
      *reinterpret_cast<bf16x8*>(
          &Klds[row * D_ + ((c8 * 8) ^ ((row & 7) << 3))]) = kk;
      const float* vsrc = vg + (size_t)(kv0 + row) * D_ + c8 * 8;
      float4 g0 = *reinterpret_cast<const float4*>(vsrc);
      float4 g1 = *reinterpret_cast<const float4*>(vsrc + 4);
      const int dbase = c8 * 8;
      Vlds[(dbase + 0) * 40 + row] = f2bf(g0.x);
      Vlds[(dbase + 1) * 40 + row] = f2bf(g0.y);
      Vlds[(dbase + 2) * 40 + row] = f2bf(g0.z);
      Vlds[(dbase + 3) * 40 + row] = f2bf(g0.w);
      Vlds[(dbase + 4) * 40 + row] = f2bf(g1.x);
      Vlds[(dbase + 5) * 40 + row] = f2bf(g1.y);
      Vlds[(dbase + 6) * 40 + row] = f2bf(g1.z);
      Vlds[(dbase + 7) * 40 + row] = f2bf(g1.w);
    }
    __syncthreads();
    f32x4 sfrag[2];
#pragma unroll
    for (int kb = 0; kb < 2; ++kb) {
      f32x4 acc = (f32x4){0.f, 0.f, 0.f, 0.f};
#pragma unroll
      for (int ks = 0; ks < 4; ++ks) {
        const int rowk = kb * 16 + l16;
        bf16x8 bk = *reinterpret_cast<const bf16x8*>(
            &Klds[rowk * D_ + (((ks * 4 + lhi) * 8) ^ ((rowk & 7) << 3))]);
        acc = __builtin_amdgcn_mfma_f32_16x16x32_bf16(aq[ks], bk, acc, 0, 0, 0);
      }
      sfrag[kb] = acc;
    }
    float mt[4];
#pragma unroll
    for (int r = 0; r < 4; ++r) mt[r] = fmaxf(sfrag[0][r], sfrag[1][r]);
#pragma unroll
    for (int off = 1; off < 16; off <<= 1)
#pragma unroll
      for (int r = 0; r < 4; ++r) mt[r] = fmaxf(mt[r], __shfl_xor(mt[r], off, 64));
    float al[4], ps[4];
#pragma unroll
    for (int r = 0; r < 4; ++r) {
      float mn = fmaxf(mrow[r], mt[r]);
      al[r] = exp2f(mrow[r] - mn);
      mrow[r] = mn;
      ps[r] = 0.f;
    }
#pragma unroll
    for (int kb = 0; kb < 2; ++kb)
#pragma unroll
      for (int r = 0; r < 4; ++r) {
        float p = exp2f(sfrag[kb][r] - mrow[r]);
        ps[r] += p;
        Plds[wid][(lhi * 4 + r) * 40 + kb * 16 + l16] = f2bf(p);
      }
#pragma unroll
    for (int off = 1; off < 16; off <<= 1)
#pragma unroll
      for (int r = 0; r < 4; ++r) ps[r] += __shfl_xor(ps[r], off, 64);
#pragma unroll
    for (int r = 0; r < 4; ++r) lrow[r] = lrow[r] * al[r] + ps[r];
#pragma unroll
    for (int i = 0; i < 8; ++i)
#pragma unroll
      for (int r = 0; r < 4; ++r) oacc[i][r] *= al[r];
    bf16x8 ap = *reinterpret_cast<const bf16x8*>(&Plds[wid][l16 * 40 + lhi * 8]);
#pragma unroll
    for (int d0 = 0; d0 < 8; ++d0) {
      bf16x8 bv = *reinterpret_cast<const bf16x8*>(
          &Vlds[(d0 * 16 + l16) * 40 + lhi * 8]);
      oacc[d0] = __builtin_amdgcn_mfma_f32_16x16x32_bf16(ap, bv, oacc[d0], 0, 0, 0);
    }
  }
#pragma unroll
  for (int r = 0; r < 4; ++r) {
    float inv = 1.0f / lrow[r];
    float* orow = out + ((size_t)bh * S_ + qrow0 + lhi * 4 + r) * D_ + l16;
#pragma unroll
    for (int d0 = 0; d0 < 8; ++d0) orow[d0 * 16] = oacc[d0][r] * inv;
  }
}

extern "C" void kernel_launch(void* const* d_in, const int* in_sizes, int n_in,
                              void* d_out, int out_size, void* d_ws, size_t ws_size,
                              hipStream_t stream) {
  (void)in_sizes; (void)n_in; (void)out_size;
  const float* q = (const float*)d_in[0];
  const float* k = (const float*)d_in[1];
  const float* v = (const float*)d_in[2];
  float* o = (float*)d_out;
  const size_t NEL = (size_t)BH * S_ * D_;
  const size_t need = NEL * 2 * sizeof(short);   // kb + vt, 33.6 MB
  if (ws_size >= need) {
    short* kb = (short*)d_ws;
    short* vt = kb + NEL;
    hipLaunchKernelGGL(prep_k, dim3(2048), dim3(256), 0, stream, k, kb);
    hipLaunchKernelGGL(prep_vt, dim3(1024), dim3(256), 0, stream, v, vt);
    hipLaunchKernelGGL(attn_fwd_v16, dim3(256), dim3(512), 0, stream, q, kb, vt, o);
  } else {
    hipLaunchKernelGGL(attn_fwd_v1, dim3(1024), dim3(256), 0, stream, q, k, v, o);
  }
}